// Round 10
// baseline (358.681 us; speedup 1.0000x reference)
//
#include <hip/hip_runtime.h>

// Round 10: single-launch fused Mamba-2 chunked SSD with per-bh tail-block
// scan and spin flags (no cooperative launch, no grid-wide barrier).
//   Per block (b,h,c), 256 thr: stage B,C,B^T,X^T (bf16, swizzled, LDS-resident
//   for the whole kernel) + cumsum; Hend=(w.X)^T.B -> ws; bump Ctr[bh]
//   (ACQ_REL agent). 32nd arriver = scanner: serial 32-chunk scan in-place
//   (Hend -> Hstart) + Hlast, release Done[bh]. Everyone overlaps G=C.B^T ->
//   S=mask*exp*G -> Yint=S.Xt (regs); then spin-acquire Done[bh], load own
//   Hstart, acc=C.Hstart, single store Y = Yint + Lam*acc.
// Deadlock-free by construction: LDS 33 KB (<=40 KB) and launch_bounds(256,4)
// (<=128 VGPR) give exactly 4 blocks/CU * 256 CU = 1024 = grid, all resident;
// no block waits before publishing its Hend.
// Coherence: __threadfence + __hip_atomic agent scope (wbl2/inv on gfx950).
// MFMA 16x16x32 bf16: A m=lane&15,k=quad*8+j; B n=lane&15,k=quad*8+j;
//                     D col=lane&15, row=quad*4+reg.
// Tiles 64x64 bf16 unpadded with 16B XOR swizzle (2-way conflicts = free):
//   elem(row,col) at row*64 + (((col>>3)^(row&7))<<3) + (col&7).
// ~50 us of dur_us is the harness poison-fill floor (measured r4/r6/r7).

constexpr int BSZ = 2, T = 2048, H = 16, P = 64, N = 64;
constexpr int L = 64, NC = T / L;   // 32 chunks per (b,h)
constexpr int NBH = BSZ * H;        // 32

using bf16x8 = __attribute__((ext_vector_type(8))) short;
using f32x4  = __attribute__((ext_vector_type(4))) float;

__device__ inline ushort f2bf(float f) {
    unsigned u = __float_as_uint(f);
    u += 0x7FFFu + ((u >> 16) & 1u);
    return (ushort)(u >> 16);
}
__device__ inline unsigned pack2(float a, float b) {
    return (unsigned)f2bf(a) | ((unsigned)f2bf(b) << 16);
}
__device__ inline float bf2f(ushort h) {
    return __uint_as_float(((unsigned)h) << 16);
}
__device__ inline int swz(int row, int col) {
    return row * 64 + ((((col >> 3) ^ (row & 7))) << 3) + (col & 7);
}

__global__ __launch_bounds__(256, 4) void fused_ssd(
    const float* __restrict__ X, const float* __restrict__ delta,
    const float* __restrict__ Bm, const float* __restrict__ Cm,
    const float* __restrict__ A_log,
    float* __restrict__ Y, float* __restrict__ Hlast,
    ushort* __restrict__ Hbuf,        // [1024][4096] bf16 tiles: Hend -> Hstart
    float* __restrict__ Dchunk,       // [1024]
    int* __restrict__ Ctr,            // [32] zeroed
    int* __restrict__ Done)           // [32] zeroed
{
    __shared__ __align__(16) ushort sC [4096];   // C [t][n]            (all phases)
    __shared__ __align__(16) ushort sBn[4096];   // B [tau][n]; then S [t][tau]
    __shared__ __align__(16) ushort sBt[4096];   // B^T [n][tau]; Hend stage; Hstart
    __shared__ __align__(16) ushort sXt[4096];   // X^T [p][tau]
    __shared__ float sSa[64], sSb[64], sLam[64], sWf[64];
    __shared__ int sOrd;

    const int tid  = threadIdx.x, lane = tid & 63, w = tid >> 6;
    const int quad = lane >> 4,   l16  = lane & 15;
    const int blk = blockIdx.x;               // ((b*NC)+c)*H + h
    const int h   = blk & (H - 1);
    const int c   = (blk >> 4) & (NC - 1);
    const int b   = blk >> 9;
    const int t0  = c * L;
    const int bh  = b * H + h;
    const int chunkid = bh * NC + c;

    // ---- stage B,C (natural, swizzled) ----
    {
        const float4* gB4 = (const float4*)(Bm + ((size_t)b * T + t0) * N);
        const float4* gC4 = (const float4*)(Cm + ((size_t)b * T + t0) * N);
        #pragma unroll
        for (int r = 0; r < 4; ++r) {
            int idx = r * 256 + tid, t = idx >> 4, n4 = idx & 15;
            int g = n4 >> 1, half = n4 & 1;
            int off = t * 64 + (((g ^ (t & 7))) << 3) + half * 4;
            float4 vb = gB4[idx], vc = gC4[idx];
            *(uint2*)&sBn[off] = make_uint2(pack2(vb.x, vb.y), pack2(vb.z, vb.w));
            *(uint2*)&sC [off] = make_uint2(pack2(vc.x, vc.y), pack2(vc.z, vc.w));
        }
    }
    // ---- stage B^T, X^T (swizzled) ----
    {
        const float* gB = Bm + ((size_t)b * T + t0) * N;
        #pragma unroll
        for (int i = 0; i < 8; ++i) {
            int tau = (w * 8 + i) * 2;
            *(unsigned*)&sBt[swz(lane, tau)] =
                pack2(gB[(size_t)tau * N + lane], gB[(size_t)(tau + 1) * N + lane]);
        }
        const float* gX = X + (((size_t)b * T + t0) * H + h) * P;
        #pragma unroll
        for (int i = 0; i < 8; ++i) {
            int tau = w * 16 + 2 * i;
            *(unsigned*)&sXt[swz(lane, tau)] =
                pack2(gX[(size_t)tau * (H * P) + lane],
                      gX[(size_t)(tau + 1) * (H * P) + lane]);
        }
    }
    if (w == 0) {
        float dl = delta[((size_t)b * T + t0 + lane) * H + h];
        float s = -__expf(A_log[h]) * dl;
        #pragma unroll
        for (int off = 1; off < 64; off <<= 1) {
            float u = __shfl_up(s, off, 64);
            if (lane >= off) s += u;
        }
        float sL  = __shfl(s, 63, 64);
        float lnd = __logf(dl);
        sSa[lane]  = s;
        sSb[lane]  = lnd - s;
        sLam[lane] = __expf(s);
        sWf[lane]  = __expf(sL + lnd - s);
        if (lane == 63) Dchunk[chunkid] = __expf(sL);
    }
    __syncthreads();

    // ---- Hend strip = (w*X)^T . B ----
    f32x4 ha[4];
    #pragma unroll
    for (int j = 0; j < 4; ++j) ha[j] = (f32x4){0.f, 0.f, 0.f, 0.f};
    #pragma unroll
    for (int ks = 0; ks < 2; ++ks) {
        const int ko = ks * 32 + quad * 8;
        const int sg = (ko >> 3) ^ (l16 & 7);
        bf16x8 xa = *(const bf16x8*)&sXt[(w * 16 + l16) * 64 + sg * 8];
        union { bf16x8 v; unsigned u[4]; } xw;
        #pragma unroll
        for (int j2 = 0; j2 < 4; ++j2)
            xw.u[j2] = pack2(bf2f((ushort)xa[2*j2])   * sWf[ko + 2*j2],
                             bf2f((ushort)xa[2*j2+1]) * sWf[ko + 2*j2+1]);
        #pragma unroll
        for (int jn = 0; jn < 4; ++jn) {
            bf16x8 bb = *(const bf16x8*)&sBt[(jn * 16 + l16) * 64 + sg * 8];
            ha[jn] = __builtin_amdgcn_mfma_f32_16x16x32_bf16(xw.v, bb, ha[jn], 0, 0, 0);
        }
    }
    __syncthreads();   // all sBt frag reads done
    #pragma unroll
    for (int jn = 0; jn < 4; ++jn)
        #pragma unroll
        for (int r = 0; r < 4; ++r)
            sBt[swz(w * 16 + quad * 4 + r, jn * 16 + l16)] = f2bf(ha[jn][r]);
    __syncthreads();
    {
        ushort* Ht = Hbuf + (size_t)chunkid * 4096;
        ((uint4*)Ht)[tid]       = ((const uint4*)sBt)[tid];
        ((uint4*)Ht)[256 + tid] = ((const uint4*)sBt)[256 + tid];
    }
    __syncthreads();   // drains vmcnt: tile fully stored

    // ---- publish + elect scanner ----
    if (tid == 0) {
        __threadfence();
        sOrd = __hip_atomic_fetch_add(&Ctr[bh], 1, __ATOMIC_ACQ_REL,
                                      __HIP_MEMORY_SCOPE_AGENT);
    }
    __syncthreads();
    const bool isScan = (sOrd == NBH - 0 - 1 + (NC - NBH));  // placeholder avoided below
    // (computed properly:)
    const bool scanner = (sOrd == NC - 1);

    // ---- scanner: serial in-place scan Hend -> Hstart + Hlast ----
    if (scanner) {
        unsigned* Hb = (unsigned*)(Hbuf + (size_t)bh * NC * 4096);
        const float* Dp = Dchunk + bh * NC;
        float hs[16];
        #pragma unroll
        for (int e = 0; e < 16; ++e) hs[e] = 0.f;
        for (int cc = 0; cc < NC; ++cc) {
            uint4* tp = (uint4*)(Hb + cc * 2048);
            uint4 t0v = tp[tid];
            uint4 t1v = tp[256 + tid];
            const float D = Dp[cc];
            uint4 s0, s1;
            unsigned tin[8] = {t0v.x, t0v.y, t0v.z, t0v.w, t1v.x, t1v.y, t1v.z, t1v.w};
            unsigned sout[8];
            #pragma unroll
            for (int j = 0; j < 8; ++j) {
                sout[j] = pack2(hs[2*j], hs[2*j+1]);
                hs[2*j]   = D * hs[2*j]   + bf2f((ushort)(tin[j] & 0xffffu));
                hs[2*j+1] = D * hs[2*j+1] + bf2f((ushort)(tin[j] >> 16));
            }
            s0 = make_uint4(sout[0], sout[1], sout[2], sout[3]);
            s1 = make_uint4(sout[4], sout[5], sout[6], sout[7]);
            tp[tid]       = s0;
            tp[256 + tid] = s1;
        }
        // Hlast (fp32, un-swizzled): thread's uint4 q covers one 16B group
        #pragma unroll
        for (int q = 0; q < 2; ++q) {
            const int u4  = q * 256 + tid;
            const int row = u4 >> 3;                       // p
            const int rg  = (u4 & 7) ^ (row & 7);          // real col group
            float* dst = Hlast + (size_t)bh * 4096 + row * 64 + rg * 8;
            *(float4*)dst       = make_float4(hs[8*q+0], hs[8*q+1], hs[8*q+2], hs[8*q+3]);
            *(float4*)(dst + 4) = make_float4(hs[8*q+4], hs[8*q+5], hs[8*q+6], hs[8*q+7]);
        }
        if (tid == 0) {
            __threadfence();
            __hip_atomic_store(&Done[bh], 1, __ATOMIC_RELEASE,
                               __HIP_MEMORY_SCOPE_AGENT);
        }
    }

    // ---- G strip = C . B^T (K=n) ----
    f32x4 g4[4];
    #pragma unroll
    for (int j = 0; j < 4; ++j) g4[j] = (f32x4){0.f, 0.f, 0.f, 0.f};
    #pragma unroll
    for (int ks = 0; ks < 2; ++ks) {
        const int ko = ks * 32 + quad * 8;
        const int sg = (ko >> 3) ^ (l16 & 7);
        bf16x8 af = *(const bf16x8*)&sC[(w * 16 + l16) * 64 + sg * 8];
        #pragma unroll
        for (int jt = 0; jt < 4; ++jt) {
            bf16x8 bfr = *(const bf16x8*)&sBn[(jt * 16 + l16) * 64 + sg * 8];
            g4[jt] = __builtin_amdgcn_mfma_f32_16x16x32_bf16(af, bfr, g4[jt], 0, 0, 0);
        }
    }
    __syncthreads();   // G reads of sBn done before S overwrites it

    // ---- S strip -> sBn alias ----
    #pragma unroll
    for (int jt = 0; jt < 4; ++jt) {
        const int tau = jt * 16 + l16;
        const float sbv = sSb[tau];
        #pragma unroll
        for (int r = 0; r < 4; ++r) {
            const int t = w * 16 + quad * 4 + r;
            float arg = (tau <= t) ? (sSa[t] + sbv) : -80.0f;
            sBn[swz(t, tau)] = f2bf(__expf(arg) * g4[jt][r]);
        }
    }
    __syncthreads();

    // ---- Yint strip = S . Xt (regs) ----
    f32x4 ya[4];
    #pragma unroll
    for (int j = 0; j < 4; ++j) ya[j] = (f32x4){0.f, 0.f, 0.f, 0.f};
    #pragma unroll
    for (int ks = 0; ks < 2; ++ks) {
        const int ko = ks * 32 + quad * 8;
        const int sg = (ko >> 3) ^ (l16 & 7);
        bf16x8 sa = *(const bf16x8*)&sBn[(w * 16 + l16) * 64 + sg * 8];
        #pragma unroll
        for (int jp = 0; jp < 4; ++jp) {
            bf16x8 xb = *(const bf16x8*)&sXt[(jp * 16 + l16) * 64 + sg * 8];
            ya[jp] = __builtin_amdgcn_mfma_f32_16x16x32_bf16(sa, xb, ya[jp], 0, 0, 0);
        }
    }

    // ---- wait for this bh's scan ----
    if (tid == 0) {
        while (__hip_atomic_load(&Done[bh], __ATOMIC_ACQUIRE,
                                 __HIP_MEMORY_SCOPE_AGENT) == 0)
            __builtin_amdgcn_s_sleep(8);
    }
    __syncthreads();

    // ---- load Hstart tile -> sBt (dead), inter GEMM ----
    {
        const uint4* Ht = (const uint4*)(Hbuf + (size_t)chunkid * 4096);
        uint4 h0 = Ht[tid], h1 = Ht[256 + tid];
        ((uint4*)sBt)[tid]       = h0;
        ((uint4*)sBt)[256 + tid] = h1;
    }
    __syncthreads();

    f32x4 acc[4];
    #pragma unroll
    for (int j = 0; j < 4; ++j) acc[j] = (f32x4){0.f, 0.f, 0.f, 0.f};
    #pragma unroll
    for (int ks = 0; ks < 2; ++ks) {
        const int ko = ks * 32 + quad * 8;
        const int sg = (ko >> 3) ^ (l16 & 7);
        bf16x8 ca = *(const bf16x8*)&sC[(w * 16 + l16) * 64 + sg * 8];
        #pragma unroll
        for (int jp = 0; jp < 4; ++jp) {
            bf16x8 hb = *(const bf16x8*)&sBt[(jp * 16 + l16) * 64 + sg * 8];
            acc[jp] = __builtin_amdgcn_mfma_f32_16x16x32_bf16(ca, hb, acc[jp], 0, 0, 0);
        }
    }

    // ---- fused Y store ----
    float* Yg = Y + (((size_t)b * T + t0) * H + h) * P;
    #pragma unroll
    for (int jp = 0; jp < 4; ++jp)
        #pragma unroll
        for (int r = 0; r < 4; ++r) {
            const int t = w * 16 + quad * 4 + r;
            Yg[(size_t)t * (H * P) + jp * 16 + l16] =
                ya[jp][r] + sLam[t] * acc[jp][r];
        }
    (void)isScan;
}

extern "C" void kernel_launch(void* const* d_in, const int* in_sizes, int n_in,
                              void* d_out, int out_size, void* d_ws, size_t ws_size,
                              hipStream_t stream) {
    const float* X     = (const float*)d_in[0];
    const float* delta = (const float*)d_in[1];
    const float* Bm    = (const float*)d_in[2];
    const float* Cm    = (const float*)d_in[3];
    const float* A_log = (const float*)d_in[4];

    float* Y     = (float*)d_out;
    float* Hlast = (float*)d_out + (size_t)BSZ * T * H * P;

    char* ws = (char*)d_ws;
    ushort* Hbuf  = (ushort*)ws;                        // 1024 * 8 KB = 8 MiB
    float* Dchunk = (float*)(ws + (8u << 20));          // 4 KiB
    int*   Ctr    = (int*)(ws + (8u << 20) + 4096);     // 32 ints
    int*   Done   = (int*)(ws + (8u << 20) + 4096 + 128);

    hipMemsetAsync(Ctr, 0, 256, stream);                // zero Ctr + Done

    fused_ssd<<<BSZ * NC * H, 256, 0, stream>>>(
        X, delta, Bm, Cm, A_log, Y, Hlast, Hbuf, Dchunk, Ctr, Done);
}

// Round 11
// 97.068 us; speedup vs baseline: 3.6952x; 3.6952x over previous
//
#include <hip/hip_runtime.h>

// Round 11: 2-launch DMA-staged Mamba-2 chunked SSD.
//   KA (=r9): per (b,h,c): swizzled bf16 tile prep (Xt), cumsum vectors,
//       Hend=(w.X)^T.B -> Hbuf; B/C bf16 tiles dumped once per (b,c).
//   K3: stage C,B,Xt via global_load_lds; EACH BLOCK scans Hend tiles of
//       chunks 0..c-1 itself (batched L2-hot loads + register scan) ->
//       Hstart packed straight into LDS (no global Hstart, no K2 kernel,
//       no inter-block signaling -- r10's spin flags caused an XCD coherence
//       storm, 310 us). c==NC-1 block also writes Hlast.
//       Then G=C.B^T -> S=mask*exp*G (alias over B) -> Yint=S.Xt + acc=C.Hst
//       -> Y = Yint + Lam*acc (single store).
// Tile format: 64x64 bf16, UNPADDED, 16B-group XOR swizzle:
//   elem(row,col) at row*64 + (((col>>3)^(row&7))<<3) + (col&7)
//   -> frag ds_read_b128 2-way conflicts only (free), DMA-compatible rows.
// MFMA 16x16x32 bf16: A m=lane&15,k=quad*8+j; B n=lane&15,k=quad*8+j;
//                     D col=lane&15, row=quad*4+reg.
// ~48-55 us of dur_us is harness poison-fill/restore floor (r4/r6/r7/r10).

constexpr int BSZ = 2, T = 2048, H = 16, P = 64, N = 64;
constexpr int L = 64, NC = T / L;   // 32 chunks per (b,h)
constexpr int LSB = 72;             // padded stride for KA-internal B^T only

using bf16x8 = __attribute__((ext_vector_type(8))) short;
using f32x4  = __attribute__((ext_vector_type(4))) float;

__device__ inline ushort f2bf(float f) {
    unsigned u = __float_as_uint(f);
    u += 0x7FFFu + ((u >> 16) & 1u);
    return (ushort)(u >> 16);
}
__device__ inline unsigned pack2(float a, float b) {
    return (unsigned)f2bf(a) | ((unsigned)f2bf(b) << 16);
}
__device__ inline float bf2f(ushort h) {
    return __uint_as_float(((unsigned)h) << 16);
}
__device__ inline int swz(int row, int col) {
    return row * 64 + ((((col >> 3) ^ (row & 7))) << 3) + (col & 7);
}

typedef __attribute__((address_space(3))) unsigned int       lds_u32;
typedef const __attribute__((address_space(1))) unsigned int glb_u32;
__device__ inline void dma16(const void* g, void* l) {
    __builtin_amdgcn_global_load_lds((glb_u32*)g, (lds_u32*)l, 16, 0, 0);
}
__device__ inline void dma4(const void* g, void* l) {
    __builtin_amdgcn_global_load_lds((glb_u32*)g, (lds_u32*)l, 4, 0, 0);
}

// ---------------- KA: prep + chunk-local end state (r9, unchanged) ----------
__global__ __launch_bounds__(256, 4) void ka_prep(
    const float* __restrict__ X, const float* __restrict__ delta,
    const float* __restrict__ Bm, const float* __restrict__ Cm,
    const float* __restrict__ A_log,
    ushort* __restrict__ Xtg, ushort* __restrict__ Hbuf,
    ushort* __restrict__ Bbf, ushort* __restrict__ Cbf,
    float* __restrict__ Vec, float* __restrict__ Dchunk)
{
    __shared__ __align__(16) ushort sXt[4096];       // [p][tau] swizzled
    __shared__ __align__(16) ushort sBt[64 * LSB];   // [n][tau] padded (internal)
    __shared__ float sWf[64];

    const int tid  = threadIdx.x, lane = tid & 63, w = tid >> 6;
    const int quad = lane >> 4,   l16  = lane & 15;
    const int blk = blockIdx.x;               // ((b*NC)+c)*H + h  (h fastest)
    const int h   = blk & (H - 1);
    const int c   = (blk >> 4) & (NC - 1);
    const int b   = blk >> 9;
    const int t0  = c * L;
    const int chunkid = (b * H + h) * NC + c;
    const int bcid    = b * NC + c;

    {   // B^T [n][tau] (padded, KA-internal)
        const float* gB = Bm + ((size_t)b * T + t0) * N;
        #pragma unroll
        for (int i = 0; i < 8; ++i) {
            int tau = (w * 8 + i) * 2;
            *(unsigned*)&sBt[lane * LSB + tau] =
                pack2(gB[(size_t)tau * N + lane], gB[(size_t)(tau + 1) * N + lane]);
        }
    }
    {   // X^T [p][tau] swizzled
        const float* gX = X + (((size_t)b * T + t0) * H + h) * P;
        #pragma unroll
        for (int i = 0; i < 8; ++i) {
            int tau = w * 16 + 2 * i;
            *(unsigned*)&sXt[swz(lane, tau)] =
                pack2(gX[(size_t)tau * (H * P) + lane],
                      gX[(size_t)(tau + 1) * (H * P) + lane]);
        }
    }
    if (h == 0) {   // dump B,C bf16 swizzled tiles (once per (b,c))
        const float4* gB4 = (const float4*)(Bm + ((size_t)b * T + t0) * N);
        const float4* gC4 = (const float4*)(Cm + ((size_t)b * T + t0) * N);
        ushort* Bt = Bbf + (size_t)bcid * 4096;
        ushort* Ct = Cbf + (size_t)bcid * 4096;
        #pragma unroll
        for (int r = 0; r < 4; ++r) {
            int idx = r * 256 + tid, t = idx >> 4, n4 = idx & 15;
            int g = n4 >> 1, half = n4 & 1;
            int off = t * 64 + (((g ^ (t & 7))) << 3) + half * 4;
            float4 vb = gB4[idx], vc = gC4[idx];
            *(uint2*)&Bt[off] = make_uint2(pack2(vb.x, vb.y), pack2(vb.z, vb.w));
            *(uint2*)&Ct[off] = make_uint2(pack2(vc.x, vc.y), pack2(vc.z, vc.w));
        }
    }
    if (w == 0) {   // cumsum + vector dumps
        float dl = delta[((size_t)b * T + t0 + lane) * H + h];
        float s = -__expf(A_log[h]) * dl;
        #pragma unroll
        for (int off = 1; off < 64; off <<= 1) {
            float u = __shfl_up(s, off, 64);
            if (lane >= off) s += u;
        }
        float sL  = __shfl(s, 63, 64);
        float lnd = __logf(dl);
        sWf[lane] = __expf(sL + lnd - s);
        float* vp = Vec + (size_t)chunkid * 192;
        vp[lane]       = s;            // sa
        vp[64 + lane]  = lnd - s;      // sb
        vp[128 + lane] = __expf(s);    // Lambda
        if (lane == 63) Dchunk[chunkid] = __expf(sL);
    }
    __syncthreads();

    // Hend strip = (w*X)^T . B
    f32x4 ha[4];
    #pragma unroll
    for (int j = 0; j < 4; ++j) ha[j] = (f32x4){0.f, 0.f, 0.f, 0.f};
    #pragma unroll
    for (int ks = 0; ks < 2; ++ks) {
        const int ko = ks * 32 + quad * 8;
        const int sg = (ko >> 3) ^ (l16 & 7);
        bf16x8 xa = *(const bf16x8*)&sXt[(w * 16 + l16) * 64 + sg * 8];
        union { bf16x8 v; unsigned u[4]; } xw;
        #pragma unroll
        for (int j2 = 0; j2 < 4; ++j2)
            xw.u[j2] = pack2(bf2f((ushort)xa[2*j2])   * sWf[ko + 2*j2],
                             bf2f((ushort)xa[2*j2+1]) * sWf[ko + 2*j2+1]);
        #pragma unroll
        for (int jn = 0; jn < 4; ++jn) {
            bf16x8 bb = *(const bf16x8*)&sBt[(jn * 16 + l16) * LSB + ko];
            ha[jn] = __builtin_amdgcn_mfma_f32_16x16x32_bf16(xw.v, bb, ha[jn], 0, 0, 0);
        }
    }

    {   // dump Xt tile
        ushort* Xtt = Xtg + (size_t)chunkid * 4096;
        #pragma unroll
        for (int i = 0; i < 2; ++i) {
            int j = i * 256 + tid;
            ((uint4*)Xtt)[j] = ((const uint4*)sXt)[j];
        }
    }
    __syncthreads();   // all sBt frag reads done
    {   // restage Hend swizzled into sBt
        #pragma unroll
        for (int jn = 0; jn < 4; ++jn)
            #pragma unroll
            for (int r = 0; r < 4; ++r)
                sBt[swz(w * 16 + quad * 4 + r, jn * 16 + l16)] = f2bf(ha[jn][r]);
    }
    __syncthreads();
    {
        ushort* Ht = Hbuf + (size_t)chunkid * 4096;
        ((uint4*)Ht)[tid]       = ((const uint4*)sBt)[tid];
        ((uint4*)Ht)[256 + tid] = ((const uint4*)sBt)[256 + tid];
    }
}

// ---------------- K3: local scan + Y ----------------
__global__ __launch_bounds__(256, 4) void k3_y(
    const ushort* __restrict__ Xtg, const ushort* __restrict__ Bbf,
    const ushort* __restrict__ Cbf, const float* __restrict__ Vec,
    const ushort* __restrict__ Hbuf, const float* __restrict__ Dchunk,
    float* __restrict__ Hlast, float* __restrict__ Y)
{
    __shared__ __align__(16) ushort sC [4096];   // C [t][n]
    __shared__ __align__(16) ushort sB [4096];   // B [tau][n]; then S [t][tau]
    __shared__ __align__(16) ushort sXt[4096];   // Xt [p][tau]
    __shared__ __align__(16) ushort sH [4096];   // Hstart [p][n] (built locally)
    __shared__ float sVec[192];                  // sa | sb | Lambda

    const int tid  = threadIdx.x, lane = tid & 63, w = tid >> 6;
    const int quad = lane >> 4,   l16  = lane & 15;
    const int blk = blockIdx.x;
    const int h   = blk & (H - 1);
    const int c   = (blk >> 4) & (NC - 1);
    const int b   = blk >> 9;
    const int t0  = c * L;
    const int bh  = b * H + h;
    const int chunkid = bh * NC + c;
    const int bcid    = b * NC + c;

    // ---- async DMA staging of C, B, Xt, Vec ----
    {
        const ushort* gsrc = nullptr;
        ushort* ldst = nullptr;
        if      (w == 0) { gsrc = Cbf + (size_t)bcid * 4096;    ldst = sC;  }
        else if (w == 1) { gsrc = Bbf + (size_t)bcid * 4096;    ldst = sB;  }
        else if (w == 2) { gsrc = Xtg + (size_t)chunkid * 4096; ldst = sXt; }
        if (w < 3) {
            const char* g = (const char*)gsrc + lane * 16;
            #pragma unroll
            for (int i = 0; i < 8; ++i)
                dma16(g + i * 1024, (char*)ldst + i * 1024);
        } else {
            const float* vp = Vec + (size_t)chunkid * 192;
            dma4(vp + lane,       sVec);
            dma4(vp + 64 + lane,  sVec + 64);
            dma4(vp + 128 + lane, sVec + 128);
        }
    }

    // ---- block-local redundant scan: Hstart = scan(Hend[0..c-1]) ----
    float hs[16];
    #pragma unroll
    for (int e = 0; e < 16; ++e) hs[e] = 0.f;
    {
        const uint4* Hb = (const uint4*)(Hbuf + (size_t)bh * NC * 4096);
        const float* Dp = Dchunk + bh * NC;
        #pragma unroll 4
        for (int cc = 0; cc < c; ++cc) {
            uint4 t0v = Hb[cc * 512 + tid];
            uint4 t1v = Hb[cc * 512 + 256 + tid];
            const float D = Dp[cc];
            unsigned tin[8] = {t0v.x, t0v.y, t0v.z, t0v.w,
                               t1v.x, t1v.y, t1v.z, t1v.w};
            #pragma unroll
            for (int j = 0; j < 8; ++j) {
                hs[2*j]   = D * hs[2*j]   + bf2f((ushort)(tin[j] & 0xffffu));
                hs[2*j+1] = D * hs[2*j+1] + bf2f((ushort)(tin[j] >> 16));
            }
        }
    }
    // pack Hstart -> sH (same uint4 slots as the swizzled tile layout)
    {
        uint4 p0 = make_uint4(pack2(hs[0], hs[1]),  pack2(hs[2], hs[3]),
                              pack2(hs[4], hs[5]),  pack2(hs[6], hs[7]));
        uint4 p1 = make_uint4(pack2(hs[8], hs[9]),  pack2(hs[10], hs[11]),
                              pack2(hs[12], hs[13]), pack2(hs[14], hs[15]));
        ((uint4*)sH)[tid]       = p0;
        ((uint4*)sH)[256 + tid] = p1;
    }
    // c == NC-1 block also produces Hlast = D[c]*Hstart + Hend[c]
    if (c == NC - 1) {
        const uint4* Hb = (const uint4*)(Hbuf + (size_t)bh * NC * 4096);
        uint4 t0v = Hb[c * 512 + tid];
        uint4 t1v = Hb[c * 512 + 256 + tid];
        const float D = Dchunk[bh * NC + c];
        unsigned tin[8] = {t0v.x, t0v.y, t0v.z, t0v.w,
                           t1v.x, t1v.y, t1v.z, t1v.w};
        float hl[16];
        #pragma unroll
        for (int j = 0; j < 8; ++j) {
            hl[2*j]   = D * hs[2*j]   + bf2f((ushort)(tin[j] & 0xffffu));
            hl[2*j+1] = D * hs[2*j+1] + bf2f((ushort)(tin[j] >> 16));
        }
        #pragma unroll
        for (int q = 0; q < 2; ++q) {
            const int u4  = q * 256 + tid;
            const int row = u4 >> 3;                  // p
            const int rg  = (u4 & 7) ^ (row & 7);     // un-swizzled col group
            float* dst = Hlast + (size_t)bh * 4096 + row * 64 + rg * 8;
            *(float4*)dst       = make_float4(hl[8*q+0], hl[8*q+1], hl[8*q+2], hl[8*q+3]);
            *(float4*)(dst + 4) = make_float4(hl[8*q+4], hl[8*q+5], hl[8*q+6], hl[8*q+7]);
        }
    }
    __syncthreads();

    // ---- G strip = C . B^T (K=n) ----
    f32x4 g4[4];
    #pragma unroll
    for (int j = 0; j < 4; ++j) g4[j] = (f32x4){0.f, 0.f, 0.f, 0.f};
    #pragma unroll
    for (int ks = 0; ks < 2; ++ks) {
        const int ko = ks * 32 + quad * 8;
        const int sg = (ko >> 3) ^ (l16 & 7);
        bf16x8 af = *(const bf16x8*)&sC[(w * 16 + l16) * 64 + sg * 8];
        #pragma unroll
        for (int jt = 0; jt < 4; ++jt) {
            bf16x8 bfr = *(const bf16x8*)&sB[(jt * 16 + l16) * 64 + sg * 8];
            g4[jt] = __builtin_amdgcn_mfma_f32_16x16x32_bf16(af, bfr, g4[jt], 0, 0, 0);
        }
    }
    __syncthreads();   // G reads of sB done before S overwrites it

    // ---- S strip -> sB alias ----
    #pragma unroll
    for (int jt = 0; jt < 4; ++jt) {
        const int tau = jt * 16 + l16;
        const float sbv = sVec[64 + tau];
        #pragma unroll
        for (int r = 0; r < 4; ++r) {
            const int t = w * 16 + quad * 4 + r;
            float arg = (tau <= t) ? (sVec[t] + sbv) : -80.0f;
            sB[swz(t, tau)] = f2bf(__expf(arg) * g4[jt][r]);
        }
    }
    __syncthreads();

    // ---- Yint = S . Xt  and  acc = C . Hstart ----
    f32x4 ya[4], acc[4];
    #pragma unroll
    for (int j = 0; j < 4; ++j) {
        ya[j]  = (f32x4){0.f, 0.f, 0.f, 0.f};
        acc[j] = (f32x4){0.f, 0.f, 0.f, 0.f};
    }
    #pragma unroll
    for (int ks = 0; ks < 2; ++ks) {
        const int ko = ks * 32 + quad * 8;
        const int sg = (ko >> 3) ^ (l16 & 7);
        bf16x8 sa = *(const bf16x8*)&sB[(w * 16 + l16) * 64 + sg * 8];
        bf16x8 ca = *(const bf16x8*)&sC[(w * 16 + l16) * 64 + sg * 8];
        #pragma unroll
        for (int jp = 0; jp < 4; ++jp) {
            bf16x8 xb = *(const bf16x8*)&sXt[(jp * 16 + l16) * 64 + sg * 8];
            bf16x8 hb = *(const bf16x8*)&sH [(jp * 16 + l16) * 64 + sg * 8];
            ya[jp]  = __builtin_amdgcn_mfma_f32_16x16x32_bf16(sa, xb, ya[jp], 0, 0, 0);
            acc[jp] = __builtin_amdgcn_mfma_f32_16x16x32_bf16(ca, hb, acc[jp], 0, 0, 0);
        }
    }

    // ---- fused Y store ----
    float* Yg = Y + (((size_t)b * T + t0) * H + h) * P;
    #pragma unroll
    for (int jp = 0; jp < 4; ++jp)
        #pragma unroll
        for (int r = 0; r < 4; ++r) {
            const int t = w * 16 + quad * 4 + r;
            Yg[(size_t)t * (H * P) + jp * 16 + l16] =
                ya[jp][r] + sVec[128 + t] * acc[jp][r];
        }
}

extern "C" void kernel_launch(void* const* d_in, const int* in_sizes, int n_in,
                              void* d_out, int out_size, void* d_ws, size_t ws_size,
                              hipStream_t stream) {
    const float* X     = (const float*)d_in[0];
    const float* delta = (const float*)d_in[1];
    const float* Bm    = (const float*)d_in[2];
    const float* Cm    = (const float*)d_in[3];
    const float* A_log = (const float*)d_in[4];

    float* Y     = (float*)d_out;
    float* Hlast = (float*)d_out + (size_t)BSZ * T * H * P;

    char* ws = (char*)d_ws;
    ushort* Hbuf = (ushort*)(ws);                          // 8 MiB
    ushort* Xtg  = (ushort*)(ws + (8u << 20));             // 8 MiB
    ushort* Bbf  = (ushort*)(ws + (16u << 20));            // 512 KiB
    ushort* Cbf  = (ushort*)(ws + (16u << 20) + (512u << 10));
    float*  Vec  = (float*)(ws + (17u << 20));             // 768 KiB
    float*  Dchunk = (float*)(ws + (18u << 20));           // 4 KiB

    const int nblk = BSZ * NC * H;   // 1024
    ka_prep<<<nblk, 256, 0, stream>>>(X, delta, Bm, Cm, A_log,
                                      Xtg, Hbuf, Bbf, Cbf, Vec, Dchunk);
    k3_y<<<nblk, 256, 0, stream>>>(Xtg, Bbf, Cbf, Vec, Hbuf, Dchunk,
                                   Hlast, Y);
}